// Round 7
// baseline (432.460 us; speedup 1.0000x reference)
//
#include <hip/hip_runtime.h>

typedef unsigned short u16;
typedef short s16x8 __attribute__((ext_vector_type(8)));
typedef float f32x4 __attribute__((ext_vector_type(4)));

#define N_NODES 4096
#define NBATCH 2
#define FIN 256
#define FOUT 64
#define NROWS (NBATCH * N_NODES)
#define NBLK (NROWS / 16)

__device__ __forceinline__ float bf2f(u16 u) {
  union { unsigned int i; float f; } v; v.i = ((unsigned int)u) << 16; return v.f;
}
__device__ __forceinline__ float asfloat(unsigned int i) {
  union { unsigned int i; float f; } v; v.i = i; return v.f;
}
__device__ __forceinline__ u16 f2bf(float f) {
  union { float f; unsigned int i; } v; v.f = f;
  unsigned int r = v.i + 0x7fffu + ((v.i >> 16) & 1u);
  return (u16)(r >> 16);
}

#define MFMA(a, b, c) __builtin_amdgcn_mfma_f32_16x16x32_bf16((a), (b), (c), 0, 0, 0)

// K0: dtype probe + stash small params as f32. flag=1 means f32 inputs.
__global__ void probe_kernel(const void* __restrict__ w2, const void* __restrict__ b2,
                             const void* __restrict__ w3, const void* __restrict__ b3,
                             const void* __restrict__ gamma, const void* __restrict__ beta,
                             int* __restrict__ flag, float* __restrict__ params) {
  const int t = threadIdx.x;  // 64
  const bool isf32 = (((const u16*)gamma)[0] == 0);
  if (t == 0) flag[0] = isf32 ? 1 : 0;
  if (isf32) {
    params[t]       = ((const float*)w2)[t];
    params[64 + t]  = ((const float*)w3)[t];
    params[128 + t] = ((const float*)gamma)[t];
    params[192 + t] = ((const float*)beta)[t];
    if (t == 0) { params[256] = ((const float*)b2)[0]; params[257] = ((const float*)b3)[0]; }
  } else {
    params[t]       = bf2f(((const u16*)w2)[t]);
    params[64 + t]  = bf2f(((const u16*)w3)[t]);
    params[128 + t] = bf2f(((const u16*)gamma)[t]);
    params[192 + t] = bf2f(((const u16*)beta)[t]);
    if (t == 0) { params[256] = bf2f(((const u16*)b2)[0]); params[257] = bf2f(((const u16*)b3)[0]); }
  }
}

// K1: projection (validated in R5/R6). bf16: MFMA -> VT channel-major bf16.
// f32: VALU fallback -> SF f32. Both write f1/f2.
__global__ __launch_bounds__(64) void proj_kernel(
    const void* __restrict__ seq, const void* __restrict__ W1,
    const int* __restrict__ flag, const float* __restrict__ params,
    u16* __restrict__ VT, float* __restrict__ SF,
    float* __restrict__ f1g, float* __restrict__ f2g) {
  __shared__ float ls[FIN];
  const int t = threadIdx.x;
  const int g0 = blockIdx.x << 4;
  const int isf32 = *flag;

  if (!isf32) {
    const int n = t & 15, q = t >> 4;
    const int b = g0 >> 12;
    const int r0 = g0 & (N_NODES - 1);
    f32x4 acc[4] = {};
    const u16* srow = (const u16*)seq + (size_t)(g0 + n) * FIN;
    const u16* w1p = (const u16*)W1;
    for (int kk = 0; kk < FIN; kk += 32) {
      s16x8 A = *(const s16x8*)(srow + kk + q * 8);
#pragma unroll
      for (int c = 0; c < 4; ++c) {
        s16x8 Bf = *(const s16x8*)(w1p + (size_t)(c * 16 + n) * FIN + kk + q * 8);
        acc[c] = MFMA(A, Bf, acc[c]);
      }
    }
    float fp1[4] = {0.f, 0.f, 0.f, 0.f}, fp2[4] = {0.f, 0.f, 0.f, 0.f};
#pragma unroll
    for (int c = 0; c < 4; ++c) {
      float w2f = params[c * 16 + n];
      float w3f = params[64 + c * 16 + n];
#pragma unroll
      for (int r = 0; r < 4; ++r) {
        float v = acc[c][r];  // C[row=q*4+r][col=n], o=c*16+n
        VT[(size_t)(b * FOUT + c * 16 + n) * N_NODES + r0 + q * 4 + r] = f2bf(v);
        fp1[r] += v * w2f;
        fp2[r] += v * w3f;
      }
    }
#pragma unroll
    for (int d = 1; d < 16; d <<= 1) {
#pragma unroll
      for (int r = 0; r < 4; ++r) {
        fp1[r] += __shfl_xor(fp1[r], d);
        fp2[r] += __shfl_xor(fp2[r], d);
      }
    }
    if (n == 0) {
#pragma unroll
      for (int r = 0; r < 4; ++r) {
        f1g[g0 + q * 4 + r] = fp1[r] + params[256];
        f2g[g0 + q * 4 + r] = fp2[r] + params[257];
      }
    }
  } else {
    for (int rr = 0; rr < 16; ++rr) {
      const int row = g0 + rr;
      float4 v = ((const float4*)seq)[(size_t)row * (FIN / 4) + t];
      ls[t * 4 + 0] = v.x; ls[t * 4 + 1] = v.y; ls[t * 4 + 2] = v.z; ls[t * 4 + 3] = v.w;
      __syncthreads();
      float acc = 0.f;
      const float4* wrow = (const float4*)W1 + (size_t)t * (FIN / 4);
      for (int k4 = 0; k4 < FIN / 4; ++k4) {
        float4 wv = wrow[k4];
        acc += ls[k4 * 4 + 0] * wv.x + ls[k4 * 4 + 1] * wv.y
             + ls[k4 * 4 + 2] * wv.z + ls[k4 * 4 + 3] * wv.w;
      }
      SF[(size_t)row * FOUT + t] = acc;
      float y1 = acc * params[t];
      float y2 = acc * params[64 + t];
#pragma unroll
      for (int d = 1; d < 64; d <<= 1) { y1 += __shfl_xor(y1, d); y2 += __shfl_xor(y2, d); }
      if (t == 0) { f1g[row] = y1 + params[256]; f2g[row] = y2 + params[257]; }
      __syncthreads();
    }
  }
}

// K2a: bf16 attention, j-split 4-way for occupancy (2048 blocks) + 8-deep bias prefetch.
// Block = (row-group g, j-quarter qd); writes partial O/l to global.
__global__ __launch_bounds__(256) void attn_bf16_kernel(
    const u16* __restrict__ bias, const int* __restrict__ flag,
    const u16* __restrict__ VT, const float* __restrict__ f1g, const float* __restrict__ f2g,
    float* __restrict__ Opart, float* __restrict__ lpart) {
  if (*flag != 0) return;   // bf16 path only
  __shared__ float Obuf[4][16][64];   // 16 KB
  __shared__ float lbuf[4][16];

  const int t = threadIdx.x;
  const int w = t >> 6, lane = t & 63;
  const int n = lane & 15, q = lane >> 4;
  const int blk = blockIdx.x;         // 2048
  const int g = blk >> 2;             // row-group 0..511
  const int qd = blk & 3;             // j-quarter
  const int b = g >> 8;
  const int row0 = (g & 255) << 4;

  const float f1 = f1g[b * N_NODES + row0 + n];
  const u16* biasRow = bias + ((size_t)(b * N_NODES + row0 + n)) * N_NODES;
  const float* f2p = f2g + b * N_NODES;
  const u16* VTb = VT + (size_t)b * FOUT * N_NODES;

  const int jbase = qd * 1024 + w * 256 + q * 8;   // wave covers 256 j in 8 steps of 32
  f32x4 acc[4] = {};
  float l_run = 0.f;

  uint4 braw[8];
#pragma unroll
  for (int s = 0; s < 8; ++s)
    braw[s] = *(const uint4*)(biasRow + jbase + s * 32);   // 8 loads in flight

#pragma unroll
  for (int s = 0; s < 8; ++s) {
    const int jj = jbase + s * 32;
    float4 f2a = *(const float4*)(f2p + jj);
    float4 f2c = *(const float4*)(f2p + jj + 4);
    float fv[8] = {f2a.x, f2a.y, f2a.z, f2a.w, f2c.x, f2c.y, f2c.z, f2c.w};
    float bb[8];
    bb[0] = asfloat(braw[s].x << 16); bb[1] = asfloat(braw[s].x & 0xffff0000u);
    bb[2] = asfloat(braw[s].y << 16); bb[3] = asfloat(braw[s].y & 0xffff0000u);
    bb[4] = asfloat(braw[s].z << 16); bb[5] = asfloat(braw[s].z & 0xffff0000u);
    bb[6] = asfloat(braw[s].w << 16); bb[7] = asfloat(braw[s].w & 0xffff0000u);
    union { s16x8 v; u16 e[8]; } A;
#pragma unroll
    for (int i = 0; i < 8; ++i) {
      float a = f1 + fv[i];
      a = fmaxf(a, 0.01f * a);            // leaky_relu
      u16 pb = f2bf(__expf(a + bb[i]));   // unnormalized weight, bf16
      A.e[i] = pb;
      l_run += bf2f(pb);                  // denominator from SAME rounded values
    }
#pragma unroll
    for (int c = 0; c < 4; ++c) {
      s16x8 Bf = *(const s16x8*)(VTb + (size_t)(c * 16 + n) * N_NODES + jj);
      acc[c] = MFMA(A.v, Bf, acc[c]);
    }
  }

  l_run += __shfl_xor(l_run, 16);
  l_run += __shfl_xor(l_run, 32);
  if (lane < 16) lbuf[w][lane] = l_run;
#pragma unroll
  for (int c = 0; c < 4; ++c)
#pragma unroll
    for (int r = 0; r < 4; ++r)
      Obuf[w][q * 4 + r][c * 16 + n] = acc[c][r];   // C[row=q*4+r][col=n]
  __syncthreads();

  const int ch = t & 63;
  const int rr = t >> 6;
#pragma unroll
  for (int i = 0; i < 4; ++i) {
    int r = rr * 4 + i;
    Opart[((size_t)(g * 4 + qd) * 16 + r) * 64 + ch] =
        Obuf[0][r][ch] + Obuf[1][r][ch] + Obuf[2][r][ch] + Obuf[3][r][ch];
  }
  if (t < 16)
    lpart[(g * 4 + qd) * 16 + t] = lbuf[0][t] + lbuf[1][t] + lbuf[2][t] + lbuf[3][t];
}

// K2b: merge j-quarter partials, normalize, write vals + BN partials (bf16 path).
__global__ __launch_bounds__(256) void attn_reduce_kernel(
    const int* __restrict__ flag, const float* __restrict__ Opart,
    const float* __restrict__ lpart, float* __restrict__ vals,
    float* __restrict__ psum, float* __restrict__ psumsq) {
  if (*flag != 0) return;
  __shared__ float sbuf[4][64];
  __shared__ float ssbuf[4][64];
  const int t = threadIdx.x;
  const int g = blockIdx.x;           // 512
  const int b = g >> 8;
  const int row0 = (g & 255) << 4;
  const int ch = t & 63, rr = t >> 6;
  float s1l = 0.f, s2l = 0.f;
#pragma unroll
  for (int i = 0; i < 4; ++i) {
    int r = rr * 4 + i;
    float L = lpart[(g * 4 + 0) * 16 + r] + lpart[(g * 4 + 1) * 16 + r]
            + lpart[(g * 4 + 2) * 16 + r] + lpart[(g * 4 + 3) * 16 + r];
    float O = Opart[((size_t)(g * 4 + 0) * 16 + r) * 64 + ch]
            + Opart[((size_t)(g * 4 + 1) * 16 + r) * 64 + ch]
            + Opart[((size_t)(g * 4 + 2) * 16 + r) * 64 + ch]
            + Opart[((size_t)(g * 4 + 3) * 16 + r) * 64 + ch];
    float v = O / L;
    vals[((size_t)(b * N_NODES + row0 + r)) * FOUT + ch] = v;
    s1l += v; s2l += v * v;
  }
  sbuf[rr][ch] = s1l; ssbuf[rr][ch] = s2l;
  __syncthreads();
  if (t < 64) {
    psum[t * NBLK + g]   = sbuf[0][t] + sbuf[1][t] + sbuf[2][t] + sbuf[3][t];
    psumsq[t * NBLK + g] = ssbuf[0][t] + ssbuf[1][t] + ssbuf[2][t] + ssbuf[3][t];
  }
}

// K2c: f32 VALU fallback attention (R5-validated), writes vals/psum/psumsq directly.
__global__ __launch_bounds__(256) void attn_f32_kernel(
    const float* __restrict__ bias, const int* __restrict__ flag,
    const float* __restrict__ SF, const float* __restrict__ f1g, const float* __restrict__ f2g,
    float* __restrict__ vals, float* __restrict__ psum, float* __restrict__ psumsq) {
  if (*flag == 0) return;   // f32 path only
  __shared__ float pbuf[16][512];
  __shared__ float part[4][16][64];
  __shared__ float lbufW[4][16];
  __shared__ float f1s[16];
  __shared__ float sbuf[4][64];
  __shared__ float ssbuf[4][64];

  const int t = threadIdx.x;
  const int w = t >> 6, lane = t & 63;
  const int blk = blockIdx.x;
  const int b = blk >> 8;
  const int row0 = (blk & 255) << 4;

  if (t < 16) f1s[t] = f1g[b * N_NODES + row0 + t];
  __syncthreads();

  const int ch = lane;
  float acc[16], rowL[16];
#pragma unroll
  for (int r = 0; r < 16; ++r) { acc[r] = 0.f; rowL[r] = 0.f; }
  const float* f2p = f2g + b * N_NODES;
  const int jl = w * 128 + lane * 2;

  for (int tile = 0; tile < 8; ++tile) {
    const int j = tile * 512 + jl;
#pragma unroll 4
    for (int r = 0; r < 16; ++r) {
      float2 bp = *(const float2*)(bias + ((size_t)(b * N_NODES + row0 + r)) * N_NODES + j);
      float2 f2v = *(const float2*)(f2p + j);
      float a0 = f1s[r] + f2v.x; a0 = fmaxf(a0, 0.01f * a0);
      float a1 = f1s[r] + f2v.y; a1 = fmaxf(a1, 0.01f * a1);
      float p0 = __expf(a0 + bp.x);
      float p1 = __expf(a1 + bp.y);
      *(float2*)&pbuf[r][jl] = make_float2(p0, p1);
      rowL[r] += p0 + p1;
    }
    __syncthreads();
    const float* SFb = SF + ((size_t)(b * N_NODES + tile * 512 + w * 128)) * FOUT + ch;
    for (int jj4 = 0; jj4 < 32; ++jj4) {
      float s0 = SFb[(jj4 * 4 + 0) * FOUT];
      float s1 = SFb[(jj4 * 4 + 1) * FOUT];
      float s2 = SFb[(jj4 * 4 + 2) * FOUT];
      float s3 = SFb[(jj4 * 4 + 3) * FOUT];
#pragma unroll
      for (int r = 0; r < 16; ++r) {
        float4 p4 = *(const float4*)&pbuf[r][w * 128 + jj4 * 4];
        acc[r] += p4.x * s0 + p4.y * s1 + p4.z * s2 + p4.w * s3;
      }
    }
    __syncthreads();
  }

#pragma unroll
  for (int r = 0; r < 16; ++r) {
    float s = rowL[r];
#pragma unroll
    for (int d = 1; d < 64; d <<= 1) s += __shfl_xor(s, d);
    if (lane == 0) lbufW[w][r] = s;
    part[w][r][ch] = acc[r];
  }
  __syncthreads();
  const int rr = t >> 6;
  float s1l = 0.f, s2l = 0.f;
#pragma unroll
  for (int i = 0; i < 4; ++i) {
    int r = rr * 4 + i;
    float L = lbufW[0][r] + lbufW[1][r] + lbufW[2][r] + lbufW[3][r];
    float v = (part[0][r][ch] + part[1][r][ch] + part[2][r][ch] + part[3][r][ch]) / L;
    vals[((size_t)(b * N_NODES + row0 + r)) * FOUT + ch] = v;
    s1l += v; s2l += v * v;
  }
  sbuf[rr][ch] = s1l; ssbuf[rr][ch] = s2l;
  __syncthreads();
  if (t < 64) {
    psum[t * NBLK + blk]   = sbuf[0][t] + sbuf[1][t] + sbuf[2][t] + sbuf[3][t];
    psumsq[t * NBLK + blk] = ssbuf[0][t] + ssbuf[1][t] + ssbuf[2][t] + ssbuf[3][t];
  }
}

// K3: parallel BN stats (validated in R5).
__global__ __launch_bounds__(256) void stats_kernel(
    const float* __restrict__ psum, const float* __restrict__ psumsq,
    const float* __restrict__ params, float* __restrict__ gsh) {
  __shared__ float red[2][4];
  const int ch = blockIdx.x;
  const int t = threadIdx.x;
  float s  = psum[ch * NBLK + t]   + psum[ch * NBLK + 256 + t];
  float ss = psumsq[ch * NBLK + t] + psumsq[ch * NBLK + 256 + t];
#pragma unroll
  for (int d = 1; d < 64; d <<= 1) { s += __shfl_xor(s, d); ss += __shfl_xor(ss, d); }
  if ((t & 63) == 0) { red[0][t >> 6] = s; red[1][t >> 6] = ss; }
  __syncthreads();
  if (t == 0) {
    float S  = red[0][0] + red[0][1] + red[0][2] + red[0][3];
    float SS = red[1][0] + red[1][1] + red[1][2] + red[1][3];
    const float inv = 1.f / (float)NROWS;
    float mean = S * inv;
    float var = SS * inv - mean * mean;
    float g = params[128 + ch] * rsqrtf(var + 1e-5f);
    gsh[ch] = g;
    gsh[64 + ch] = params[192 + ch] - mean * g;
  }
}

// K4: normalize + ELU -> output (dtype per flag).
__global__ __launch_bounds__(256) void norm_kernel(const float* __restrict__ vals,
                                                   const float* __restrict__ gsh,
                                                   const int* __restrict__ flag,
                                                   void* __restrict__ out) {
  int base = (blockIdx.x * 256 + threadIdx.x) * 4;
  float4 v = *(const float4*)(vals + base);
  int ch = base & 63;
  float x0 = v.x * gsh[ch + 0] + gsh[64 + ch + 0];
  float x1 = v.y * gsh[ch + 1] + gsh[64 + ch + 1];
  float x2 = v.z * gsh[ch + 2] + gsh[64 + ch + 2];
  float x3 = v.w * gsh[ch + 3] + gsh[64 + ch + 3];
  x0 = x0 > 0.f ? x0 : __expf(x0) - 1.f;
  x1 = x1 > 0.f ? x1 : __expf(x1) - 1.f;
  x2 = x2 > 0.f ? x2 : __expf(x2) - 1.f;
  x3 = x3 > 0.f ? x3 : __expf(x3) - 1.f;
  if (*flag) {
    float4 o; o.x = x0; o.y = x1; o.z = x2; o.w = x3;
    *(float4*)((float*)out + base) = o;
  } else {
    ushort4 o; o.x = f2bf(x0); o.y = f2bf(x1); o.z = f2bf(x2); o.w = f2bf(x3);
    *(ushort4*)((u16*)out + base) = o;
  }
}

extern "C" void kernel_launch(void* const* d_in, const int* in_sizes, int n_in,
                              void* d_out, int out_size, void* d_ws, size_t ws_size,
                              hipStream_t stream) {
  const void* seq   = d_in[0];
  const void* bias  = d_in[1];
  const void* W1    = d_in[2];
  const void* w2    = d_in[3];
  const void* b2    = d_in[4];
  const void* w3    = d_in[5];
  const void* b3    = d_in[6];
  const void* gamma = d_in[7];
  const void* beta  = d_in[8];

  char* ws = (char*)d_ws;
  int*   flag   = (int*)ws;                            // @0
  float* params = (float*)(ws + 256);                  // 258 f32
  float* gsh    = (float*)(ws + 2048);                 // 128 f32
  u16*   VT     = (u16*)(ws + 4096);                   // 1 MB  [B][FOUT][N] bf16
  float* SF     = (float*)(ws + 4096 + (1u << 20));    // 2 MB  [NROWS][FOUT] f32 (f32 path)
  float* f1g    = SF + (size_t)NROWS * FOUT;           // 32 KB
  float* f2g    = f1g + NROWS;                         // 32 KB
  float* vals   = f2g + NROWS;                         // 2 MB
  float* psum   = vals + (size_t)NROWS * FOUT;         // 128 KB [64][NBLK]
  float* psumsq = psum + 64 * NBLK;                    // 128 KB [64][NBLK]
  float* Opart  = psumsq + 64 * NBLK;                  // 8 MB   [512*4*16][64]
  float* lpart  = Opart + (size_t)NBLK * 4 * 16 * 64;  // 128 KB [512*4*16]

  probe_kernel<<<1, 64, 0, stream>>>(w2, b2, w3, b3, gamma, beta, flag, params);
  proj_kernel<<<NROWS / 16, 64, 0, stream>>>(seq, W1, flag, params, VT, SF, f1g, f2g);
  attn_bf16_kernel<<<NBLK * 4, 256, 0, stream>>>((const u16*)bias, flag, VT, f1g, f2g,
                                                 Opart, lpart);
  attn_f32_kernel<<<NBLK, 256, 0, stream>>>((const float*)bias, flag, SF, f1g, f2g,
                                            vals, psum, psumsq);
  attn_reduce_kernel<<<NBLK, 256, 0, stream>>>(flag, Opart, lpart, vals, psum, psumsq);
  stats_kernel<<<64, 256, 0, stream>>>(psum, psumsq, params, gsh);
  norm_kernel<<<(NROWS * FOUT) / 1024, 256, 0, stream>>>(vals, gsh, flag, d_out);
}

// Round 8
// 326.024 us; speedup vs baseline: 1.3265x; 1.3265x over previous
//
#include <hip/hip_runtime.h>

typedef unsigned short u16;
typedef short s16x8 __attribute__((ext_vector_type(8)));
typedef float f32x4 __attribute__((ext_vector_type(4)));

#define N_NODES 4096
#define NBATCH 2
#define FIN 256
#define FOUT 64
#define NROWS (NBATCH * N_NODES)
#define NBLK (NROWS / 16)   // 512 row-groups of 16

__device__ __forceinline__ float bf2f(u16 u) {
  union { unsigned int i; float f; } v; v.i = ((unsigned int)u) << 16; return v.f;
}
__device__ __forceinline__ u16 f2bf(float f) {
  union { float f; unsigned int i; } v; v.f = f;
  unsigned int r = v.i + 0x7fffu + ((v.i >> 16) & 1u);
  return (u16)(r >> 16);
}

#define MFMA(a, b, c) __builtin_amdgcn_mfma_f32_16x16x32_bf16((a), (b), (c), 0, 0, 0)

// K0: init self-check flag (ws is poisoned each call).
__global__ void init_kernel(int* __restrict__ ok) { if (threadIdx.x == 0) ok[0] = 1; }

// K1: projection, parallel VALU. Block = 4 rows (one wave per row); lane = out-channel.
__global__ __launch_bounds__(256) void proj_kernel(
    const float* __restrict__ seq, const float* __restrict__ W1,
    const float* __restrict__ w2, const float* __restrict__ b2,
    const float* __restrict__ w3, const float* __restrict__ b3,
    float* __restrict__ SF, float* __restrict__ f1g, float* __restrict__ f2g) {
  __shared__ float ls[4][FIN];
  const int t = threadIdx.x;
  const int w = t >> 6, lane = t & 63;
  const int row = blockIdx.x * 4 + w;
  {
    float4 v = ((const float4*)seq)[(size_t)row * (FIN / 4) + lane];
    ls[w][lane * 4 + 0] = v.x; ls[w][lane * 4 + 1] = v.y;
    ls[w][lane * 4 + 2] = v.z; ls[w][lane * 4 + 3] = v.w;
  }
  __syncthreads();
  float acc = 0.f;
  const float4* wrow = (const float4*)W1 + (size_t)lane * (FIN / 4);
  for (int k4 = 0; k4 < FIN / 4; ++k4) {
    float4 wv = wrow[k4];
    acc += ls[w][k4 * 4 + 0] * wv.x + ls[w][k4 * 4 + 1] * wv.y
         + ls[w][k4 * 4 + 2] * wv.z + ls[w][k4 * 4 + 3] * wv.w;
  }
  SF[(size_t)row * FOUT + lane] = acc;
  float y1 = acc * w2[lane];
  float y2 = acc * w3[lane];
#pragma unroll
  for (int d = 1; d < 64; d <<= 1) { y1 += __shfl_xor(y1, d); y2 += __shfl_xor(y2, d); }
  if (lane == 0) { f1g[row] = y1 + b2[0]; f2g[row] = y2 + b3[0]; }
}

// K2: transpose SF -> VT bf16 channel-major [b][ch][node] (for MFMA B-fragments).
__global__ __launch_bounds__(256) void vt_kernel(const float* __restrict__ SF,
                                                 u16* __restrict__ VT) {
  __shared__ float tile[64][65];
  const int t = threadIdx.x;
  const int r0 = blockIdx.x * 64;            // 128 blocks; never crosses b boundary
  const int b = r0 >> 12;
  const int rl = t >> 6, ch = t & 63;
#pragma unroll
  for (int i = 0; i < 16; ++i)
    tile[i * 4 + rl][ch] = SF[(size_t)(r0 + i * 4 + rl) * FOUT + ch];
  __syncthreads();
  const int chw = t >> 2, seg = t & 3;       // 16 nodes per (ch, seg)
  u16* dst = VT + (size_t)(b * FOUT + chw) * N_NODES + (r0 & (N_NODES - 1)) + seg * 16;
#pragma unroll
  for (int u = 0; u < 4; ++u) {
    ushort4 x;
    x.x = f2bf(tile[seg * 16 + u * 4 + 0][chw]);
    x.y = f2bf(tile[seg * 16 + u * 4 + 1][chw]);
    x.z = f2bf(tile[seg * 16 + u * 4 + 2][chw]);
    x.w = f2bf(tile[seg * 16 + u * 4 + 3][chw]);
    *(ushort4*)(dst + u * 4) = x;
  }
}

// K3: MFMA attention. Block = (row-group g, j-quarter qd); 2048 blocks.
// P built in MFMA A-layout registers; rolling 4-deep f32 bias prefetch.
__global__ __launch_bounds__(256) void attn_mfma_kernel(
    const float* __restrict__ bias, const u16* __restrict__ VT,
    const float* __restrict__ f1g, const float* __restrict__ f2g,
    float* __restrict__ Opart, float* __restrict__ lpart) {
  __shared__ float Obuf[4][16][64];
  __shared__ float lbuf[4][16];
  const int t = threadIdx.x;
  const int w = t >> 6, lane = t & 63;
  const int n = lane & 15, q = lane >> 4;
  const int blk = blockIdx.x;
  const int g = blk >> 2, qd = blk & 3;
  const int b = g >> 8, row0 = (g & 255) << 4;

  const float f1 = f1g[b * N_NODES + row0 + n];
  const float* biasRow = bias + (size_t)(b * N_NODES + row0 + n) * N_NODES;
  const float* f2p = f2g + b * N_NODES;
  const u16* VTb = VT + (size_t)b * FOUT * N_NODES;

  const int jbase = qd * 1024 + w * 256 + q * 8;   // wave: 256 j in 8 steps of 32
  f32x4 acc[4] = {};
  float l_run = 0.f;

  float4 pba[4], pbc[4];
#pragma unroll
  for (int s = 0; s < 4; ++s) {
    pba[s] = *(const float4*)(biasRow + jbase + s * 32);
    pbc[s] = *(const float4*)(biasRow + jbase + s * 32 + 4);
  }
#pragma unroll
  for (int s = 0; s < 8; ++s) {
    const int jj = jbase + s * 32;
    float4 ba = pba[s & 3], bc = pbc[s & 3];
    if (s < 4) {
      pba[s] = *(const float4*)(biasRow + jbase + (s + 4) * 32);
      pbc[s] = *(const float4*)(biasRow + jbase + (s + 4) * 32 + 4);
    }
    float4 f2a = *(const float4*)(f2p + jj);
    float4 f2c = *(const float4*)(f2p + jj + 4);
    float fv[8] = {f2a.x, f2a.y, f2a.z, f2a.w, f2c.x, f2c.y, f2c.z, f2c.w};
    float bb[8] = {ba.x, ba.y, ba.z, ba.w, bc.x, bc.y, bc.z, bc.w};
    union { s16x8 v; u16 e[8]; } A;
#pragma unroll
    for (int i = 0; i < 8; ++i) {
      float a = f1 + fv[i];
      a = fmaxf(a, 0.01f * a);            // leaky_relu
      u16 pb = f2bf(__expf(a + bb[i]));   // unnormalized weight, bf16
      A.e[i] = pb;
      l_run += bf2f(pb);                  // denominator from SAME rounded values
    }
#pragma unroll
    for (int c = 0; c < 4; ++c) {
      s16x8 Bf = *(const s16x8*)(VTb + (size_t)(c * 16 + n) * N_NODES + jj);
      acc[c] = MFMA(A.v, Bf, acc[c]);
    }
  }

  l_run += __shfl_xor(l_run, 16);
  l_run += __shfl_xor(l_run, 32);
  if (lane < 16) lbuf[w][lane] = l_run;
#pragma unroll
  for (int c = 0; c < 4; ++c)
#pragma unroll
    for (int r = 0; r < 4; ++r)
      Obuf[w][q * 4 + r][c * 16 + n] = acc[c][r];   // C[row=q*4+r][col=n]
  __syncthreads();

  const int ch = t & 63;
  const int rr = t >> 6;
#pragma unroll
  for (int i = 0; i < 4; ++i) {
    int r = rr * 4 + i;
    Opart[((size_t)(g * 4 + qd) * 16 + r) * 64 + ch] =
        Obuf[0][r][ch] + Obuf[1][r][ch] + Obuf[2][r][ch] + Obuf[3][r][ch];
  }
  if (t < 16)
    lpart[(g * 4 + qd) * 16 + t] = lbuf[0][t] + lbuf[1][t] + lbuf[2][t] + lbuf[3][t];
}

// K4: self-check. 8 blocks: rows {0,5} of group 0, all 4 j-quarters, recomputed in
// f32 VALU and compared against MFMA partials. Clears ok on mismatch.
__global__ __launch_bounds__(256) void check_kernel(
    const float* __restrict__ bias, const float* __restrict__ SF,
    const float* __restrict__ f1g, const float* __restrict__ f2g,
    const float* __restrict__ Opart, const float* __restrict__ lpart,
    int* __restrict__ ok) {
  __shared__ float red[4][64];
  __shared__ float lred[4];
  const int t = threadIdx.x, ch = t & 63, seg = t >> 6;
  const int qd = blockIdx.x & 3;
  const int rchk = (blockIdx.x >> 2) * 5;           // row 0 or row 5 (q=1,r=1)
  const float f1 = f1g[rchk];
  float accO = 0.f, accL = 0.f;
  const int j0 = qd * 1024 + seg * 256;
  for (int i = 0; i < 256; ++i) {
    int j = j0 + i;
    float s = f1 + f2g[j];
    s = fmaxf(s, 0.01f * s);
    float p = __expf(s + bias[(size_t)rchk * N_NODES + j]);
    accO += p * SF[(size_t)j * FOUT + ch];
    accL += p;
  }
  red[seg][ch] = accO;
  if (ch == 0) lred[seg] = accL;
  __syncthreads();
  if (t < 64) {
    float O = red[0][t] + red[1][t] + red[2][t] + red[3][t];
    float L = lred[0] + lred[1] + lred[2] + lred[3];
    float Om = Opart[((size_t)qd * 16 + rchk) * 64 + t];
    float Lm = lpart[qd * 16 + rchk];
    if (fabsf(O - Om) > 0.05f * L || fabsf(L - Lm) > 0.02f * L) atomicAnd(ok, 0);
  }
}

// K5: merge j-quarter partials -> vals + BN partials (only if MFMA verified ok).
__global__ __launch_bounds__(256) void attn_reduce_kernel(
    const int* __restrict__ ok, const float* __restrict__ Opart,
    const float* __restrict__ lpart, float* __restrict__ vals,
    float* __restrict__ psum, float* __restrict__ psumsq) {
  if (*ok == 0) return;
  __shared__ float sbuf[4][64];
  __shared__ float ssbuf[4][64];
  const int t = threadIdx.x;
  const int g = blockIdx.x;
  const int b = g >> 8, row0 = (g & 255) << 4;
  const int ch = t & 63, rr = t >> 6;
  float s1l = 0.f, s2l = 0.f;
#pragma unroll
  for (int i = 0; i < 4; ++i) {
    int r = rr * 4 + i;
    float L = lpart[(g * 4 + 0) * 16 + r] + lpart[(g * 4 + 1) * 16 + r]
            + lpart[(g * 4 + 2) * 16 + r] + lpart[(g * 4 + 3) * 16 + r];
    float O = Opart[((size_t)(g * 4 + 0) * 16 + r) * 64 + ch]
            + Opart[((size_t)(g * 4 + 1) * 16 + r) * 64 + ch]
            + Opart[((size_t)(g * 4 + 2) * 16 + r) * 64 + ch]
            + Opart[((size_t)(g * 4 + 3) * 16 + r) * 64 + ch];
    float v = O / L;
    vals[((size_t)(b * N_NODES + row0 + r)) * FOUT + ch] = v;
    s1l += v; s2l += v * v;
  }
  sbuf[rr][ch] = s1l; ssbuf[rr][ch] = s2l;
  __syncthreads();
  if (t < 64) {
    psum[t * NBLK + g]   = sbuf[0][t] + sbuf[1][t] + sbuf[2][t] + sbuf[3][t];
    psumsq[t * NBLK + g] = ssbuf[0][t] + ssbuf[1][t] + ssbuf[2][t] + ssbuf[3][t];
  }
}

// K6: f32 VALU fallback attention (R4/R5-validated). Runs only if MFMA check failed.
__global__ __launch_bounds__(256) void attn_valu_kernel(
    const float* __restrict__ bias, const int* __restrict__ ok,
    const float* __restrict__ SF, const float* __restrict__ f1g, const float* __restrict__ f2g,
    float* __restrict__ vals, float* __restrict__ psum, float* __restrict__ psumsq) {
  if (*ok != 0) return;
  __shared__ float pbuf[16][512];
  __shared__ float part[4][16][64];
  __shared__ float lbufW[4][16];
  __shared__ float f1s[16];
  __shared__ float sbuf[4][64];
  __shared__ float ssbuf[4][64];

  const int t = threadIdx.x;
  const int w = t >> 6, lane = t & 63;
  const int blk = blockIdx.x;
  const int b = blk >> 8;
  const int row0 = (blk & 255) << 4;

  if (t < 16) f1s[t] = f1g[b * N_NODES + row0 + t];
  __syncthreads();

  const int ch = lane;
  float acc[16], rowL[16];
#pragma unroll
  for (int r = 0; r < 16; ++r) { acc[r] = 0.f; rowL[r] = 0.f; }
  const float* f2p = f2g + b * N_NODES;
  const int jl = w * 128 + lane * 2;

  for (int tile = 0; tile < 8; ++tile) {
    const int j = tile * 512 + jl;
#pragma unroll 4
    for (int r = 0; r < 16; ++r) {
      float2 bp = *(const float2*)(bias + ((size_t)(b * N_NODES + row0 + r)) * N_NODES + j);
      float2 f2v = *(const float2*)(f2p + j);
      float a0 = f1s[r] + f2v.x; a0 = fmaxf(a0, 0.01f * a0);
      float a1 = f1s[r] + f2v.y; a1 = fmaxf(a1, 0.01f * a1);
      float p0 = __expf(a0 + bp.x);
      float p1 = __expf(a1 + bp.y);
      *(float2*)&pbuf[r][jl] = make_float2(p0, p1);
      rowL[r] += p0 + p1;
    }
    __syncthreads();
    const float* SFb = SF + ((size_t)(b * N_NODES + tile * 512 + w * 128)) * FOUT + ch;
    for (int jj4 = 0; jj4 < 32; ++jj4) {
      float s0 = SFb[(jj4 * 4 + 0) * FOUT];
      float s1 = SFb[(jj4 * 4 + 1) * FOUT];
      float s2 = SFb[(jj4 * 4 + 2) * FOUT];
      float s3 = SFb[(jj4 * 4 + 3) * FOUT];
#pragma unroll
      for (int r = 0; r < 16; ++r) {
        float4 p4 = *(const float4*)&pbuf[r][w * 128 + jj4 * 4];
        acc[r] += p4.x * s0 + p4.y * s1 + p4.z * s2 + p4.w * s3;
      }
    }
    __syncthreads();
  }

#pragma unroll
  for (int r = 0; r < 16; ++r) {
    float s = rowL[r];
#pragma unroll
    for (int d = 1; d < 64; d <<= 1) s += __shfl_xor(s, d);
    if (lane == 0) lbufW[w][r] = s;
    part[w][r][ch] = acc[r];
  }
  __syncthreads();
  const int rr = t >> 6;
  float s1l = 0.f, s2l = 0.f;
#pragma unroll
  for (int i = 0; i < 4; ++i) {
    int r = rr * 4 + i;
    float L = lbufW[0][r] + lbufW[1][r] + lbufW[2][r] + lbufW[3][r];
    float v = (part[0][r][ch] + part[1][r][ch] + part[2][r][ch] + part[3][r][ch]) / L;
    vals[((size_t)(b * N_NODES + row0 + r)) * FOUT + ch] = v;
    s1l += v; s2l += v * v;
  }
  sbuf[rr][ch] = s1l; ssbuf[rr][ch] = s2l;
  __syncthreads();
  if (t < 64) {
    psum[t * NBLK + blk]   = sbuf[0][t] + sbuf[1][t] + sbuf[2][t] + sbuf[3][t];
    psumsq[t * NBLK + blk] = ssbuf[0][t] + ssbuf[1][t] + ssbuf[2][t] + ssbuf[3][t];
  }
}

// K7: parallel BN stats (validated).
__global__ __launch_bounds__(256) void stats_kernel(
    const float* __restrict__ psum, const float* __restrict__ psumsq,
    const float* __restrict__ gamma, const float* __restrict__ beta,
    float* __restrict__ gsh) {
  __shared__ float red[2][4];
  const int ch = blockIdx.x;
  const int t = threadIdx.x;
  float s  = psum[ch * NBLK + t]   + psum[ch * NBLK + 256 + t];
  float ss = psumsq[ch * NBLK + t] + psumsq[ch * NBLK + 256 + t];
#pragma unroll
  for (int d = 1; d < 64; d <<= 1) { s += __shfl_xor(s, d); ss += __shfl_xor(ss, d); }
  if ((t & 63) == 0) { red[0][t >> 6] = s; red[1][t >> 6] = ss; }
  __syncthreads();
  if (t == 0) {
    float S  = red[0][0] + red[0][1] + red[0][2] + red[0][3];
    float SS = red[1][0] + red[1][1] + red[1][2] + red[1][3];
    const float inv = 1.f / (float)NROWS;
    float mean = S * inv;
    float var = SS * inv - mean * mean;
    float g = gamma[ch] * rsqrtf(var + 1e-5f);
    gsh[ch] = g;
    gsh[64 + ch] = beta[ch] - mean * g;
  }
}

// K8: normalize + ELU -> f32 output.
__global__ __launch_bounds__(256) void norm_kernel(const float* __restrict__ vals,
                                                   const float* __restrict__ gsh,
                                                   float* __restrict__ out) {
  int base = (blockIdx.x * 256 + threadIdx.x) * 4;
  float4 v = *(const float4*)(vals + base);
  int ch = base & 63;
  float x0 = v.x * gsh[ch + 0] + gsh[64 + ch + 0];
  float x1 = v.y * gsh[ch + 1] + gsh[64 + ch + 1];
  float x2 = v.z * gsh[ch + 2] + gsh[64 + ch + 2];
  float x3 = v.w * gsh[ch + 3] + gsh[64 + ch + 3];
  x0 = x0 > 0.f ? x0 : __expf(x0) - 1.f;
  x1 = x1 > 0.f ? x1 : __expf(x1) - 1.f;
  x2 = x2 > 0.f ? x2 : __expf(x2) - 1.f;
  x3 = x3 > 0.f ? x3 : __expf(x3) - 1.f;
  float4 o; o.x = x0; o.y = x1; o.z = x2; o.w = x3;
  *(float4*)(out + base) = o;
}

extern "C" void kernel_launch(void* const* d_in, const int* in_sizes, int n_in,
                              void* d_out, int out_size, void* d_ws, size_t ws_size,
                              hipStream_t stream) {
  const float* seq   = (const float*)d_in[0];
  const float* bias  = (const float*)d_in[1];
  const float* W1    = (const float*)d_in[2];
  const float* w2    = (const float*)d_in[3];
  const float* b2    = (const float*)d_in[4];
  const float* w3    = (const float*)d_in[5];
  const float* b3    = (const float*)d_in[6];
  const float* gamma = (const float*)d_in[7];
  const float* beta  = (const float*)d_in[8];

  char* ws = (char*)d_ws;
  int*   ok     = (int*)ws;                            // @0
  float* gsh    = (float*)(ws + 2048);                 // 128 f32
  float* SF     = (float*)(ws + 4096);                 // 2 MB   [NROWS][FOUT]
  float* f1g    = SF + (size_t)NROWS * FOUT;           // 32 KB
  float* f2g    = f1g + NROWS;                         // 32 KB
  float* vals   = f2g + NROWS;                         // 2 MB
  float* psum   = vals + (size_t)NROWS * FOUT;         // 128 KB [64][NBLK]
  float* psumsq = psum + 64 * NBLK;                    // 128 KB [64][NBLK]
  u16*   VT     = (u16*)(psumsq + 64 * NBLK);          // 1 MB   [B][FOUT][N] bf16
  float* Opart  = (float*)(VT + (size_t)NBATCH * FOUT * N_NODES);  // 8 MB
  float* lpart  = Opart + (size_t)NBLK * 4 * 16 * 64;  // 128 KB

  init_kernel<<<1, 64, 0, stream>>>(ok);
  proj_kernel<<<NROWS / 4, 256, 0, stream>>>(seq, W1, w2, b2, w3, b3, SF, f1g, f2g);
  vt_kernel<<<NROWS / 64, 256, 0, stream>>>(SF, VT);
  attn_mfma_kernel<<<NBLK * 4, 256, 0, stream>>>(bias, VT, f1g, f2g, Opart, lpart);
  check_kernel<<<8, 256, 0, stream>>>(bias, SF, f1g, f2g, Opart, lpart, ok);
  attn_reduce_kernel<<<NBLK, 256, 0, stream>>>(ok, Opart, lpart, vals, psum, psumsq);
  attn_valu_kernel<<<NBLK, 256, 0, stream>>>(bias, ok, SF, f1g, f2g, vals, psum, psumsq);
  stats_kernel<<<64, 256, 0, stream>>>(psum, psumsq, gamma, beta, gsh);
  norm_kernel<<<(NROWS * FOUT) / 1024, 256, 0, stream>>>(vals, gsh, (float*)d_out);
}

// Round 9
// 323.140 us; speedup vs baseline: 1.3383x; 1.0089x over previous
//
#include <hip/hip_runtime.h>

typedef unsigned short u16;
typedef short s16x8 __attribute__((ext_vector_type(8)));
typedef float f32x4 __attribute__((ext_vector_type(4)));

#define N_NODES 4096
#define NBATCH 2
#define FIN 256
#define FOUT 64
#define NROWS (NBATCH * N_NODES)
#define NBLK (NROWS / 16)   // 512 row-groups of 16

__device__ __forceinline__ float bf2f(u16 u) {
  union { unsigned int i; float f; } v; v.i = ((unsigned int)u) << 16; return v.f;
}
__device__ __forceinline__ u16 f2bf(float f) {
  union { float f; unsigned int i; } v; v.f = f;
  unsigned int r = v.i + 0x7fffu + ((v.i >> 16) & 1u);
  return (u16)(r >> 16);
}

#define MFMA(a, b, c) __builtin_amdgcn_mfma_f32_16x16x32_bf16((a), (b), (c), 0, 0, 0)

// K0: init self-check flag (ws is poisoned each call).
__global__ void init_kernel(int* __restrict__ ok) { if (threadIdx.x == 0) ok[0] = 1; }

// K1: projection, parallel VALU. Block = 4 rows (one wave per row); lane = out-channel.
__global__ __launch_bounds__(256) void proj_kernel(
    const float* __restrict__ seq, const float* __restrict__ W1,
    const float* __restrict__ w2, const float* __restrict__ b2,
    const float* __restrict__ w3, const float* __restrict__ b3,
    float* __restrict__ SF, float* __restrict__ f1g, float* __restrict__ f2g) {
  __shared__ float ls[4][FIN];
  const int t = threadIdx.x;
  const int w = t >> 6, lane = t & 63;
  const int row = blockIdx.x * 4 + w;
  {
    float4 v = ((const float4*)seq)[(size_t)row * (FIN / 4) + lane];
    ls[w][lane * 4 + 0] = v.x; ls[w][lane * 4 + 1] = v.y;
    ls[w][lane * 4 + 2] = v.z; ls[w][lane * 4 + 3] = v.w;
  }
  __syncthreads();
  float acc = 0.f;
  const float4* wrow = (const float4*)W1 + (size_t)lane * (FIN / 4);
  for (int k4 = 0; k4 < FIN / 4; ++k4) {
    float4 wv = wrow[k4];
    acc += ls[w][k4 * 4 + 0] * wv.x + ls[w][k4 * 4 + 1] * wv.y
         + ls[w][k4 * 4 + 2] * wv.z + ls[w][k4 * 4 + 3] * wv.w;
  }
  SF[(size_t)row * FOUT + lane] = acc;
  float y1 = acc * w2[lane];
  float y2 = acc * w3[lane];
#pragma unroll
  for (int d = 1; d < 64; d <<= 1) { y1 += __shfl_xor(y1, d); y2 += __shfl_xor(y2, d); }
  if (lane == 0) { f1g[row] = y1 + b2[0]; f2g[row] = y2 + b3[0]; }
}

// K2: transpose SF -> VT bf16 channel-major [b][ch][node] (for MFMA B-fragments).
__global__ __launch_bounds__(256) void vt_kernel(const float* __restrict__ SF,
                                                 u16* __restrict__ VT) {
  __shared__ float tile[64][65];
  const int t = threadIdx.x;
  const int r0 = blockIdx.x * 64;            // 128 blocks; never crosses b boundary
  const int b = r0 >> 12;
  const int rl = t >> 6, ch = t & 63;
#pragma unroll
  for (int i = 0; i < 16; ++i)
    tile[i * 4 + rl][ch] = SF[(size_t)(r0 + i * 4 + rl) * FOUT + ch];
  __syncthreads();
  const int chw = t >> 2, seg = t & 3;       // 16 nodes per (ch, seg)
  u16* dst = VT + (size_t)(b * FOUT + chw) * N_NODES + (r0 & (N_NODES - 1)) + seg * 16;
#pragma unroll
  for (int u = 0; u < 4; ++u) {
    ushort4 x;
    x.x = f2bf(tile[seg * 16 + u * 4 + 0][chw]);
    x.y = f2bf(tile[seg * 16 + u * 4 + 1][chw]);
    x.z = f2bf(tile[seg * 16 + u * 4 + 2][chw]);
    x.w = f2bf(tile[seg * 16 + u * 4 + 3][chw]);
    *(ushort4*)(dst + u * 4) = x;
  }
}

// K3: MFMA attention, pipelined. Block = (row-group g, j-quarter qd); 2048 blocks.
// f2 staged in LDS (off the vmcnt chain); VT double-buffered 1 step ahead;
// bias prefetched 4-deep. P built in MFMA A-layout registers.
__global__ __launch_bounds__(256, 4) void attn_mfma_kernel(
    const float* __restrict__ bias, const u16* __restrict__ VT,
    const float* __restrict__ f1g, const float* __restrict__ f2g,
    float* __restrict__ Opart, float* __restrict__ lpart) {
  __shared__ float f2s[1024];         // 4 KB: f2 for this j-quarter
  __shared__ float Obuf[4][16][64];   // 16 KB
  __shared__ float lbuf[4][16];
  const int t = threadIdx.x;
  const int w = t >> 6, lane = t & 63;
  const int n = lane & 15, q = lane >> 4;
  const int blk = blockIdx.x;
  const int g = blk >> 2, qd = blk & 3;
  const int b = g >> 8, row0 = (g & 255) << 4;

  // cooperative f2 stage (256 threads x 4 floats)
  {
    float4 v = *(const float4*)(f2g + b * N_NODES + qd * 1024 + t * 4);
    *(float4*)&f2s[t * 4] = v;
  }
  __syncthreads();

  const float f1 = f1g[b * N_NODES + row0 + n];
  const float* biasRow = bias + (size_t)(b * N_NODES + row0 + n) * N_NODES;
  const u16* VTb = VT + (size_t)b * FOUT * N_NODES;

  const int jbase = qd * 1024 + w * 256 + q * 8;   // global j
  const int jloc = w * 256 + q * 8;                // index into f2s
  f32x4 acc[4] = {};
  float l_run = 0.f;

  // bias prefetch 4-deep (2 loads/step)
  float4 pba[4], pbc[4];
#pragma unroll
  for (int s = 0; s < 4; ++s) {
    pba[s] = *(const float4*)(biasRow + jbase + s * 32);
    pbc[s] = *(const float4*)(biasRow + jbase + s * 32 + 4);
  }
  // VT double-buffer: buf0 holds step s (s even), buf1 holds s odd
  s16x8 vt0[4], vt1[4];
#pragma unroll
  for (int c = 0; c < 4; ++c)
    vt0[c] = *(const s16x8*)(VTb + (size_t)(c * 16 + n) * N_NODES + jbase);

#pragma unroll
  for (int s = 0; s < 8; ++s) {
    const int jj = jbase + s * 32;
    float4 ba = pba[s & 3], bc = pbc[s & 3];
    if (s < 4) {
      pba[s] = *(const float4*)(biasRow + jbase + (s + 4) * 32);
      pbc[s] = *(const float4*)(biasRow + jbase + (s + 4) * 32 + 4);
    }
    if (s < 7) {   // prefetch VT for s+1 into the other buffer
#pragma unroll
      for (int c = 0; c < 4; ++c) {
        s16x8 v = *(const s16x8*)(VTb + (size_t)(c * 16 + n) * N_NODES + jj + 32);
        if (s & 1) vt0[c] = v; else vt1[c] = v;
      }
    }
    float4 fa = *(const float4*)&f2s[jloc + s * 32];
    float4 fc = *(const float4*)&f2s[jloc + s * 32 + 4];
    float fv[8] = {fa.x, fa.y, fa.z, fa.w, fc.x, fc.y, fc.z, fc.w};
    float bb[8] = {ba.x, ba.y, ba.z, ba.w, bc.x, bc.y, bc.z, bc.w};
    union { s16x8 v; u16 e[8]; } A;
#pragma unroll
    for (int i = 0; i < 8; ++i) {
      float a = f1 + fv[i];
      a = fmaxf(a, 0.01f * a);            // leaky_relu
      u16 pb = f2bf(__expf(a + bb[i]));   // unnormalized weight, bf16
      A.e[i] = pb;
      l_run += bf2f(pb);                  // denominator from SAME rounded values
    }
#pragma unroll
    for (int c = 0; c < 4; ++c) {
      s16x8 Bf = (s & 1) ? vt1[c] : vt0[c];
      acc[c] = MFMA(A.v, Bf, acc[c]);
    }
  }

  l_run += __shfl_xor(l_run, 16);
  l_run += __shfl_xor(l_run, 32);
  if (lane < 16) lbuf[w][lane] = l_run;
#pragma unroll
  for (int c = 0; c < 4; ++c)
#pragma unroll
    for (int r = 0; r < 4; ++r)
      Obuf[w][q * 4 + r][c * 16 + n] = acc[c][r];   // C[row=q*4+r][col=n]
  __syncthreads();

  const int ch = t & 63;
  const int rr = t >> 6;
#pragma unroll
  for (int i = 0; i < 4; ++i) {
    int r = rr * 4 + i;
    Opart[((size_t)(g * 4 + qd) * 16 + r) * 64 + ch] =
        Obuf[0][r][ch] + Obuf[1][r][ch] + Obuf[2][r][ch] + Obuf[3][r][ch];
  }
  if (t < 16)
    lpart[(g * 4 + qd) * 16 + t] = lbuf[0][t] + lbuf[1][t] + lbuf[2][t] + lbuf[3][t];
}

// K4: self-check. 8 blocks: rows {0,5} of group 0, all 4 j-quarters, recomputed in
// f32 VALU and compared against MFMA partials. Clears ok on mismatch.
__global__ __launch_bounds__(256) void check_kernel(
    const float* __restrict__ bias, const float* __restrict__ SF,
    const float* __restrict__ f1g, const float* __restrict__ f2g,
    const float* __restrict__ Opart, const float* __restrict__ lpart,
    int* __restrict__ ok) {
  __shared__ float red[4][64];
  __shared__ float lred[4];
  const int t = threadIdx.x, ch = t & 63, seg = t >> 6;
  const int qd = blockIdx.x & 3;
  const int rchk = (blockIdx.x >> 2) * 5;           // row 0 or row 5 (q=1,r=1)
  const float f1 = f1g[rchk];
  float accO = 0.f, accL = 0.f;
  const int j0 = qd * 1024 + seg * 256;
  for (int i = 0; i < 256; ++i) {
    int j = j0 + i;
    float s = f1 + f2g[j];
    s = fmaxf(s, 0.01f * s);
    float p = __expf(s + bias[(size_t)rchk * N_NODES + j]);
    accO += p * SF[(size_t)j * FOUT + ch];
    accL += p;
  }
  red[seg][ch] = accO;
  if (ch == 0) lred[seg] = accL;
  __syncthreads();
  if (t < 64) {
    float O = red[0][t] + red[1][t] + red[2][t] + red[3][t];
    float L = lred[0] + lred[1] + lred[2] + lred[3];
    float Om = Opart[((size_t)qd * 16 + rchk) * 64 + t];
    float Lm = lpart[qd * 16 + rchk];
    if (fabsf(O - Om) > 0.05f * L || fabsf(L - Lm) > 0.02f * L) atomicAnd(ok, 0);
  }
}

// K5: merge j-quarter partials -> vals + BN partials (only if MFMA verified ok).
__global__ __launch_bounds__(256) void attn_reduce_kernel(
    const int* __restrict__ ok, const float* __restrict__ Opart,
    const float* __restrict__ lpart, float* __restrict__ vals,
    float* __restrict__ psum, float* __restrict__ psumsq) {
  if (*ok == 0) return;
  __shared__ float sbuf[4][64];
  __shared__ float ssbuf[4][64];
  const int t = threadIdx.x;
  const int g = blockIdx.x;
  const int b = g >> 8, row0 = (g & 255) << 4;
  const int ch = t & 63, rr = t >> 6;
  float s1l = 0.f, s2l = 0.f;
#pragma unroll
  for (int i = 0; i < 4; ++i) {
    int r = rr * 4 + i;
    float L = lpart[(g * 4 + 0) * 16 + r] + lpart[(g * 4 + 1) * 16 + r]
            + lpart[(g * 4 + 2) * 16 + r] + lpart[(g * 4 + 3) * 16 + r];
    float O = Opart[((size_t)(g * 4 + 0) * 16 + r) * 64 + ch]
            + Opart[((size_t)(g * 4 + 1) * 16 + r) * 64 + ch]
            + Opart[((size_t)(g * 4 + 2) * 16 + r) * 64 + ch]
            + Opart[((size_t)(g * 4 + 3) * 16 + r) * 64 + ch];
    float v = O / L;
    vals[((size_t)(b * N_NODES + row0 + r)) * FOUT + ch] = v;
    s1l += v; s2l += v * v;
  }
  sbuf[rr][ch] = s1l; ssbuf[rr][ch] = s2l;
  __syncthreads();
  if (t < 64) {
    psum[t * NBLK + g]   = sbuf[0][t] + sbuf[1][t] + sbuf[2][t] + sbuf[3][t];
    psumsq[t * NBLK + g] = ssbuf[0][t] + ssbuf[1][t] + ssbuf[2][t] + ssbuf[3][t];
  }
}

// K6: f32 VALU fallback attention (R4/R5-validated). Runs only if MFMA check failed.
__global__ __launch_bounds__(256) void attn_valu_kernel(
    const float* __restrict__ bias, const int* __restrict__ ok,
    const float* __restrict__ SF, const float* __restrict__ f1g, const float* __restrict__ f2g,
    float* __restrict__ vals, float* __restrict__ psum, float* __restrict__ psumsq) {
  if (*ok != 0) return;
  __shared__ float pbuf[16][512];
  __shared__ float part[4][16][64];
  __shared__ float lbufW[4][16];
  __shared__ float f1s[16];
  __shared__ float sbuf[4][64];
  __shared__ float ssbuf[4][64];

  const int t = threadIdx.x;
  const int w = t >> 6, lane = t & 63;
  const int blk = blockIdx.x;
  const int b = blk >> 8;
  const int row0 = (blk & 255) << 4;

  if (t < 16) f1s[t] = f1g[b * N_NODES + row0 + t];
  __syncthreads();

  const int ch = lane;
  float acc[16], rowL[16];
#pragma unroll
  for (int r = 0; r < 16; ++r) { acc[r] = 0.f; rowL[r] = 0.f; }
  const float* f2p = f2g + b * N_NODES;
  const int jl = w * 128 + lane * 2;

  for (int tile = 0; tile < 8; ++tile) {
    const int j = tile * 512 + jl;
#pragma unroll 4
    for (int r = 0; r < 16; ++r) {
      float2 bp = *(const float2*)(bias + ((size_t)(b * N_NODES + row0 + r)) * N_NODES + j);
      float2 f2v = *(const float2*)(f2p + j);
      float a0 = f1s[r] + f2v.x; a0 = fmaxf(a0, 0.01f * a0);
      float a1 = f1s[r] + f2v.y; a1 = fmaxf(a1, 0.01f * a1);
      float p0 = __expf(a0 + bp.x);
      float p1 = __expf(a1 + bp.y);
      *(float2*)&pbuf[r][jl] = make_float2(p0, p1);
      rowL[r] += p0 + p1;
    }
    __syncthreads();
    const float* SFb = SF + ((size_t)(b * N_NODES + tile * 512 + w * 128)) * FOUT + ch;
    for (int jj4 = 0; jj4 < 32; ++jj4) {
      float s0 = SFb[(jj4 * 4 + 0) * FOUT];
      float s1 = SFb[(jj4 * 4 + 1) * FOUT];
      float s2 = SFb[(jj4 * 4 + 2) * FOUT];
      float s3 = SFb[(jj4 * 4 + 3) * FOUT];
#pragma unroll
      for (int r = 0; r < 16; ++r) {
        float4 p4 = *(const float4*)&pbuf[r][w * 128 + jj4 * 4];
        acc[r] += p4.x * s0 + p4.y * s1 + p4.z * s2 + p4.w * s3;
      }
    }
    __syncthreads();
  }

#pragma unroll
  for (int r = 0; r < 16; ++r) {
    float s = rowL[r];
#pragma unroll
    for (int d = 1; d < 64; d <<= 1) s += __shfl_xor(s, d);
    if (lane == 0) lbufW[w][r] = s;
    part[w][r][ch] = acc[r];
  }
  __syncthreads();
  const int rr = t >> 6;
  float s1l = 0.f, s2l = 0.f;
#pragma unroll
  for (int i = 0; i < 4; ++i) {
    int r = rr * 4 + i;
    float L = lbufW[0][r] + lbufW[1][r] + lbufW[2][r] + lbufW[3][r];
    float v = (part[0][r][ch] + part[1][r][ch] + part[2][r][ch] + part[3][r][ch]) / L;
    vals[((size_t)(b * N_NODES + row0 + r)) * FOUT + ch] = v;
    s1l += v; s2l += v * v;
  }
  sbuf[rr][ch] = s1l; ssbuf[rr][ch] = s2l;
  __syncthreads();
  if (t < 64) {
    psum[t * NBLK + blk]   = sbuf[0][t] + sbuf[1][t] + sbuf[2][t] + sbuf[3][t];
    psumsq[t * NBLK + blk] = ssbuf[0][t] + ssbuf[1][t] + ssbuf[2][t] + ssbuf[3][t];
  }
}

// K7: parallel BN stats (validated).
__global__ __launch_bounds__(256) void stats_kernel(
    const float* __restrict__ psum, const float* __restrict__ psumsq,
    const float* __restrict__ gamma, const float* __restrict__ beta,
    float* __restrict__ gsh) {
  __shared__ float red[2][4];
  const int ch = blockIdx.x;
  const int t = threadIdx.x;
  float s  = psum[ch * NBLK + t]   + psum[ch * NBLK + 256 + t];
  float ss = psumsq[ch * NBLK + t] + psumsq[ch * NBLK + 256 + t];
#pragma unroll
  for (int d = 1; d < 64; d <<= 1) { s += __shfl_xor(s, d); ss += __shfl_xor(ss, d); }
  if ((t & 63) == 0) { red[0][t >> 6] = s; red[1][t >> 6] = ss; }
  __syncthreads();
  if (t == 0) {
    float S  = red[0][0] + red[0][1] + red[0][2] + red[0][3];
    float SS = red[1][0] + red[1][1] + red[1][2] + red[1][3];
    const float inv = 1.f / (float)NROWS;
    float mean = S * inv;
    float var = SS * inv - mean * mean;
    float g = gamma[ch] * rsqrtf(var + 1e-5f);
    gsh[ch] = g;
    gsh[64 + ch] = beta[ch] - mean * g;
  }
}

// K8: normalize + ELU -> f32 output.
__global__ __launch_bounds__(256) void norm_kernel(const float* __restrict__ vals,
                                                   const float* __restrict__ gsh,
                                                   float* __restrict__ out) {
  int base = (blockIdx.x * 256 + threadIdx.x) * 4;
  float4 v = *(const float4*)(vals + base);
  int ch = base & 63;
  float x0 = v.x * gsh[ch + 0] + gsh[64 + ch + 0];
  float x1 = v.y * gsh[ch + 1] + gsh[64 + ch + 1];
  float x2 = v.z * gsh[ch + 2] + gsh[64 + ch + 2];
  float x3 = v.w * gsh[ch + 3] + gsh[64 + ch + 3];
  x0 = x0 > 0.f ? x0 : __expf(x0) - 1.f;
  x1 = x1 > 0.f ? x1 : __expf(x1) - 1.f;
  x2 = x2 > 0.f ? x2 : __expf(x2) - 1.f;
  x3 = x3 > 0.f ? x3 : __expf(x3) - 1.f;
  float4 o; o.x = x0; o.y = x1; o.z = x2; o.w = x3;
  *(float4*)(out + base) = o;
}

extern "C" void kernel_launch(void* const* d_in, const int* in_sizes, int n_in,
                              void* d_out, int out_size, void* d_ws, size_t ws_size,
                              hipStream_t stream) {
  const float* seq   = (const float*)d_in[0];
  const float* bias  = (const float*)d_in[1];
  const float* W1    = (const float*)d_in[2];
  const float* w2    = (const float*)d_in[3];
  const float* b2    = (const float*)d_in[4];
  const float* w3    = (const float*)d_in[5];
  const float* b3    = (const float*)d_in[6];
  const float* gamma = (const float*)d_in[7];
  const float* beta  = (const float*)d_in[8];

  char* ws = (char*)d_ws;
  int*   ok     = (int*)ws;                            // @0
  float* gsh    = (float*)(ws + 2048);                 // 128 f32
  float* SF     = (float*)(ws + 4096);                 // 2 MB   [NROWS][FOUT]
  float* f1g    = SF + (size_t)NROWS * FOUT;           // 32 KB
  float* f2g    = f1g + NROWS;                         // 32 KB
  float* vals   = f2g + NROWS;                         // 2 MB
  float* psum   = vals + (size_t)NROWS * FOUT;         // 128 KB [64][NBLK]
  float* psumsq = psum + 64 * NBLK;                    // 128 KB [64][NBLK]
  u16*   VT     = (u16*)(psumsq + 64 * NBLK);          // 1 MB   [B][FOUT][N] bf16
  float* Opart  = (float*)(VT + (size_t)NBATCH * FOUT * N_NODES);  // 8 MB
  float* lpart  = Opart + (size_t)NBLK * 4 * 16 * 64;  // 128 KB

  init_kernel<<<1, 64, 0, stream>>>(ok);
  proj_kernel<<<NROWS / 4, 256, 0, stream>>>(seq, W1, w2, b2, w3, b3, SF, f1g, f2g);
  vt_kernel<<<NROWS / 64, 256, 0, stream>>>(SF, VT);
  attn_mfma_kernel<<<NBLK * 4, 256, 0, stream>>>(bias, VT, f1g, f2g, Opart, lpart);
  check_kernel<<<8, 256, 0, stream>>>(bias, SF, f1g, f2g, Opart, lpart, ok);
  attn_reduce_kernel<<<NBLK, 256, 0, stream>>>(ok, Opart, lpart, vals, psum, psumsq);
  attn_valu_kernel<<<NBLK, 256, 0, stream>>>(bias, ok, SF, f1g, f2g, vals, psum, psumsq);
  stats_kernel<<<64, 256, 0, stream>>>(psum, psumsq, gamma, beta, gsh);
  norm_kernel<<<(NROWS * FOUT) / 1024, 256, 0, stream>>>(vals, gsh, (float*)d_out);
}